// Round 1
// baseline (687.546 us; speedup 1.0000x reference)
//
#include <hip/hip_runtime.h>

typedef __bf16 bf16x8 __attribute__((ext_vector_type(8)));
typedef __bf16 bf16x4 __attribute__((ext_vector_type(4)));
typedef float  f32x4  __attribute__((ext_vector_type(4)));

#define DEVI __device__ __forceinline__

DEVI bf16x8 ld8(const __bf16* p) { return *reinterpret_cast<const bf16x8*>(p); }
DEVI f32x4 mfma16(bf16x8 a, bf16x8 b, f32x4 c) {
  return __builtin_amdgcn_mfma_f32_16x16x32_bf16(a, b, c, 0, 0, 0);
}

// ---------- x fp32 -> bf16 ----------
__global__ void k_cvt(const float* __restrict__ in, __bf16* __restrict__ out, int n4) {
  int i = blockIdx.x * blockDim.x + threadIdx.x;
  if (i >= n4) return;
  f32x4 v = reinterpret_cast<const f32x4*>(in)[i];
  bf16x4 o;
  o[0] = (__bf16)v[0]; o[1] = (__bf16)v[1]; o[2] = (__bf16)v[2]; o[3] = (__bf16)v[3];
  reinterpret_cast<bf16x4*>(out)[i] = o;
}

// ---------- transpose fp32 [R][C] -> bf16 [C][R] (optionally hi+lo split) ----------
template<bool LO>
__global__ void k_tr(const float* __restrict__ in, __bf16* __restrict__ oh,
                     __bf16* __restrict__ ol, int R, int C) {
  __shared__ float t[32][33];
  const float* im = in + (size_t)blockIdx.z * R * C;
  __bf16* ohm = oh + (size_t)blockIdx.z * R * C;
  __bf16* olm = LO ? (ol + (size_t)blockIdx.z * R * C) : nullptr;
  int c0 = blockIdx.x * 32, r0 = blockIdx.y * 32;
  int tx = threadIdx.x & 31, ty = threadIdx.x >> 5;
  #pragma unroll
  for (int k = 0; k < 32; k += 8)
    t[ty + k][tx] = im[(size_t)(r0 + ty + k) * C + c0 + tx];
  __syncthreads();
  #pragma unroll
  for (int k = 0; k < 32; k += 8) {
    float v = t[tx][ty + k];                       // = in[r0+tx][c0+ty+k]
    size_t o = (size_t)(c0 + ty + k) * R + r0 + tx;
    __bf16 h = (__bf16)v;
    ohm[o] = h;
    if (LO) olm[o] = (__bf16)(v - (float)h);
  }
}

// ---------- QKV projection: xb[4096,256] x Wt[which][h][e][d] -> Q,K (scaled Q), Vt ----------
__global__ __launch_bounds__(256) void k_qkv(
    const __bf16* __restrict__ xb, const __bf16* __restrict__ Wt,
    const float* __restrict__ bq, const float* __restrict__ bk, const float* __restrict__ bv,
    __bf16* __restrict__ Qb, __bf16* __restrict__ Kb, __bf16* __restrict__ Vtb) {
  const int w = threadIdx.x >> 6, lane = threadIdx.x & 63;
  const int g = lane >> 4, qc = lane & 15;
  const int which = blockIdx.z >> 3, h = blockIdx.z & 7;
  const int m0 = blockIdx.x * 64 + w * 16;
  const int n0 = blockIdx.y * 64;
  const __bf16* Wm = Wt + ((size_t)blockIdx.z << 16);
  const float* bias = (which == 0 ? bq : which == 1 ? bk : bv) + h * 256;
  f32x4 acc[4] = {};
  const __bf16* ap = xb + (m0 + qc) * 256 + g * 8;
  #pragma unroll
  for (int kk = 0; kk < 8; kk++) {
    bf16x8 af = ld8(ap + kk * 32);
    #pragma unroll
    for (int nt = 0; nt < 4; nt++) {
      bf16x8 bf = ld8(Wm + (n0 + nt * 16 + qc) * 256 + kk * 32 + g * 8);
      acc[nt] = mfma16(af, bf, acc[nt]);
    }
  }
  const int b = m0 >> 11, s0 = (m0 & 2047);
  const int bh = b * 8 + h;
  #pragma unroll
  for (int nt = 0; nt < 4; nt++) {
    const int e = n0 + nt * 16 + qc;
    const float be = bias[e];
    if (which == 2) {                // V: write transposed Vt[bh][e][s]
      bf16x4 pk;
      #pragma unroll
      for (int r = 0; r < 4; r++) pk[r] = (__bf16)(acc[nt][r] + be);
      *reinterpret_cast<bf16x4*>(Vtb + ((bh * 256 + e) * 2048 + s0 + g * 4)) = pk;
    } else {
      const float sc = (which == 0) ? 0.0625f : 1.0f;   // fold 1/sqrt(D) into Q
      __bf16* Out = (which == 0) ? Qb : Kb;
      #pragma unroll
      for (int r = 0; r < 4; r++)
        Out[(bh * 2048 + s0 + g * 4 + r) * 256 + e] = (__bf16)((acc[nt][r] + be) * sc);
    }
  }
}

// ---------- flash attention: 4 waves x 16 q-rows, swapped QK^T, online softmax ----------
__global__ __launch_bounds__(256, 2) void k_attn(
    const __bf16* __restrict__ Qb, const __bf16* __restrict__ Kb,
    const __bf16* __restrict__ Vtb, __bf16* __restrict__ Oh, __bf16* __restrict__ Ol) {
  __shared__ __align__(16) __bf16 P[4][16][32];
  const int w = threadIdx.x >> 6, lane = threadIdx.x & 63;
  const int g = lane >> 4, qc = lane & 15;
  const int bh = blockIdx.x;
  const int qbase = blockIdx.y * 64 + w * 16;
  const __bf16* Qp = Qb + (bh * 2048 + qbase) * 256;
  const __bf16* Kp = Kb + bh * 2048 * 256;
  const __bf16* Vp = Vtb + bh * 256 * 2048;
  bf16x8 qf[8];
  #pragma unroll
  for (int kk = 0; kk < 8; kk++) qf[kk] = ld8(Qp + qc * 256 + kk * 32 + g * 8);
  f32x4 acc[16] = {};
  float m = -1e30f, l = 0.f;
  for (int t = 0; t < 64; t++) {
    const int kv0 = t * 32;
    f32x4 st0 = {}, st1 = {};
    const __bf16* Kt = Kp + kv0 * 256 + g * 8;
    #pragma unroll
    for (int kk = 0; kk < 8; kk++) {
      bf16x8 k0 = ld8(Kt + qc * 256 + kk * 32);
      bf16x8 k1 = ld8(Kt + (16 + qc) * 256 + kk * 32);
      st0 = mfma16(k0, qf[kk], st0);     // S^T[kv=4g+r][q=qc]
      st1 = mfma16(k1, qf[kk], st1);     // S^T[16+kv][q=qc]
    }
    float rmax = fmaxf(fmaxf(fmaxf(st0[0], st0[1]), fmaxf(st0[2], st0[3])),
                       fmaxf(fmaxf(st1[0], st1[1]), fmaxf(st1[2], st1[3])));
    rmax = fmaxf(rmax, __shfl_xor(rmax, 16));
    rmax = fmaxf(rmax, __shfl_xor(rmax, 32));
    const bool nm = rmax > m;
    const float m_new = nm ? rmax : m;
    float p0[4], p1[4];
    #pragma unroll
    for (int r = 0; r < 4; r++) {
      p0[r] = __expf(st0[r] - m_new);
      p1[r] = __expf(st1[r] - m_new);
    }
    float rs = ((p0[0] + p0[1]) + (p0[2] + p0[3])) + ((p1[0] + p1[1]) + (p1[2] + p1[3]));
    rs += __shfl_xor(rs, 16);
    rs += __shfl_xor(rs, 32);
    if (__any(nm)) {
      const float alpha = __expf(m - m_new);
      l = l * alpha + rs;
      m = m_new;
      const float a0 = __shfl(alpha, g * 4 + 0);   // softmax state lives at q=lane&15;
      const float a1 = __shfl(alpha, g * 4 + 1);   // O rows live at q=4g+r -> broadcast
      const float a2 = __shfl(alpha, g * 4 + 2);
      const float a3 = __shfl(alpha, g * 4 + 3);
      #pragma unroll
      for (int dt = 0; dt < 16; dt++) {
        acc[dt][0] *= a0; acc[dt][1] *= a1; acc[dt][2] *= a2; acc[dt][3] *= a3;
      }
    } else {
      l += rs;
    }
    bf16x4 pk0, pk1;
    #pragma unroll
    for (int r = 0; r < 4; r++) { pk0[r] = (__bf16)p0[r]; pk1[r] = (__bf16)p1[r]; }
    *reinterpret_cast<bf16x4*>(&P[w][qc][g * 4]) = pk0;        // P[q][kv] per-wave
    *reinterpret_cast<bf16x4*>(&P[w][qc][16 + g * 4]) = pk1;
    const bf16x8 pf = ld8(&P[w][qc][g * 8]);                   // A-frag for PV
    #pragma unroll
    for (int dt = 0; dt < 16; dt++) {
      bf16x8 vf = ld8(Vp + (dt * 16 + qc) * 2048 + kv0 + g * 8);
      acc[dt] = mfma16(pf, vf, acc[dt]);                       // O[q=4g+r][d=dt*16+qc]
    }
    __syncthreads();   // keep waves on the same K/V tile for L1 reuse
  }
  float linv[4];
  #pragma unroll
  for (int r = 0; r < 4; r++) linv[r] = 1.f / __shfl(l, g * 4 + r);
  const int b = bh >> 3, h = bh & 7;
  #pragma unroll
  for (int dt = 0; dt < 16; dt++) {
    const int d = dt * 16 + qc;
    #pragma unroll
    for (int r = 0; r < 4; r++) {
      const float v = acc[dt][r] * linv[r];
      const int off = b * (2048 * 2048) + (qbase + g * 4 + r) * 2048 + h * 256 + d;
      const __bf16 hi = (__bf16)v;
      Oh[off] = hi;
      Ol[off] = (__bf16)(v - (float)hi);   // split for high-precision output GEMM
    }
  }
}

// ---------- output projection: concat[4096,2048] x Wo[2048,256], split-bf16 (3 terms) ----------
__global__ __launch_bounds__(256) void k_out(
    const __bf16* __restrict__ Oh, const __bf16* __restrict__ Ol,
    const __bf16* __restrict__ Wh, const __bf16* __restrict__ Wl,
    const float* __restrict__ bo, float* __restrict__ out) {
  const int w = threadIdx.x >> 6, lane = threadIdx.x & 63;
  const int g = lane >> 4, qc = lane & 15;
  const int m0 = blockIdx.x * 64 + w * 16, n0 = blockIdx.y * 64;
  f32x4 acc[4] = {};
  const __bf16* ah_p = Oh + (m0 + qc) * 2048 + g * 8;
  const __bf16* al_p = Ol + (m0 + qc) * 2048 + g * 8;
  for (int kk = 0; kk < 64; kk++) {
    bf16x8 ah = ld8(ah_p + kk * 32);
    bf16x8 al = ld8(al_p + kk * 32);
    #pragma unroll
    for (int nt = 0; nt < 4; nt++) {
      const int nrow = (n0 + nt * 16 + qc) * 2048 + kk * 32 + g * 8;
      bf16x8 bh = ld8(Wh + nrow);
      bf16x8 bl = ld8(Wl + nrow);
      acc[nt] = mfma16(ah, bh, acc[nt]);
      acc[nt] = mfma16(al, bh, acc[nt]);
      acc[nt] = mfma16(ah, bl, acc[nt]);
    }
  }
  #pragma unroll
  for (int nt = 0; nt < 4; nt++) {
    const int n = n0 + nt * 16 + qc;
    const float bb = bo[n];
    #pragma unroll
    for (int r = 0; r < 4; r++)
      out[(m0 + g * 4 + r) * 256 + n] = acc[nt][r] + bb;
  }
}

extern "C" void kernel_launch(void* const* d_in, const int* in_sizes, int n_in,
                              void* d_out, int out_size, void* d_ws, size_t ws_size,
                              hipStream_t stream) {
  const float* x  = (const float*)d_in[0];
  const float* Wq = (const float*)d_in[1];
  const float* bq = (const float*)d_in[2];
  const float* Wk = (const float*)d_in[3];
  const float* bk = (const float*)d_in[4];
  const float* Wv = (const float*)d_in[5];
  const float* bv = (const float*)d_in[6];
  const float* Wo = (const float*)d_in[7];
  const float* bo = (const float*)d_in[8];
  char* p = (char*)d_ws;
  __bf16* xb  = (__bf16*)(p);                          // 2 MB  [4096][256]
  __bf16* Wt  = (__bf16*)(p + (2ull  << 20));          // 3 MB  [3][8][256 e][256 d]
  __bf16* Woh = (__bf16*)(p + (5ull  << 20));          // 1 MB  [256 n][2048 k]
  __bf16* Wol = (__bf16*)(p + (6ull  << 20));          // 1 MB
  __bf16* Qb  = (__bf16*)(p + (7ull  << 20));          // 16 MB [bh][s][d]  (pre-scaled)
  __bf16* Kb  = (__bf16*)(p + (23ull << 20));          // 16 MB [bh][s][d]
  __bf16* Vtb = (__bf16*)(p + (39ull << 20));          // 16 MB [bh][d][s]
  __bf16* Ohb = (__bf16*)(p + (55ull << 20));          // 16 MB [bs][h*d] hi
  __bf16* Olb = (__bf16*)(p + (71ull << 20));          // 16 MB [bs][h*d] lo

  k_cvt<<<dim3(1024), dim3(256), 0, stream>>>(x, xb, 262144);
  k_tr<false><<<dim3(8, 8, 8),  dim3(256), 0, stream>>>(Wq, Wt + 0 * 524288, nullptr, 256, 256);
  k_tr<false><<<dim3(8, 8, 8),  dim3(256), 0, stream>>>(Wk, Wt + 1 * 524288, nullptr, 256, 256);
  k_tr<false><<<dim3(8, 8, 8),  dim3(256), 0, stream>>>(Wv, Wt + 2 * 524288, nullptr, 256, 256);
  k_tr<true ><<<dim3(8, 64, 1), dim3(256), 0, stream>>>(Wo, Woh, Wol, 2048, 256);
  k_qkv<<<dim3(64, 4, 24), dim3(256), 0, stream>>>(xb, Wt, bq, bk, bv, Qb, Kb, Vtb);
  k_attn<<<dim3(16, 32), dim3(256), 0, stream>>>(Qb, Kb, Vtb, Ohb, Olb);
  k_out<<<dim3(64, 4), dim3(256), 0, stream>>>(Ohb, Olb, Woh, Wol, bo, (float*)d_out);
}

// Round 2
// 348.681 us; speedup vs baseline: 1.9718x; 1.9718x over previous
//
#include <hip/hip_runtime.h>

typedef __bf16 bf16x8 __attribute__((ext_vector_type(8)));
typedef __bf16 bf16x4 __attribute__((ext_vector_type(4)));
typedef float  f32x4  __attribute__((ext_vector_type(4)));
typedef float  f32x16 __attribute__((ext_vector_type(16)));

#define DEVI __device__ __forceinline__

DEVI bf16x8 ld8(const __bf16* p) { return *reinterpret_cast<const bf16x8*>(p); }
DEVI f32x4 mfma16(bf16x8 a, bf16x8 b, f32x4 c) {
  return __builtin_amdgcn_mfma_f32_16x16x32_bf16(a, b, c, 0, 0, 0);
}
DEVI f32x16 mfma32(bf16x8 a, bf16x8 b, f32x16 c) {
  return __builtin_amdgcn_mfma_f32_32x32x16_bf16(a, b, c, 0, 0, 0);
}
DEVI void gl_lds16(const void* g, void* l) {
  __builtin_amdgcn_global_load_lds((__attribute__((address_space(1))) void*)g,
                                   (__attribute__((address_space(3))) void*)l, 16, 0, 0);
}

// ---------- x fp32 -> bf16 ----------
__global__ void k_cvt(const float* __restrict__ in, __bf16* __restrict__ out, int n4) {
  int i = blockIdx.x * blockDim.x + threadIdx.x;
  if (i >= n4) return;
  f32x4 v = reinterpret_cast<const f32x4*>(in)[i];
  bf16x4 o;
  o[0] = (__bf16)v[0]; o[1] = (__bf16)v[1]; o[2] = (__bf16)v[2]; o[3] = (__bf16)v[3];
  reinterpret_cast<bf16x4*>(out)[i] = o;
}

// ---------- transpose fp32 [R][C] -> bf16 [C][R] (optionally hi+lo split) ----------
template<bool LO>
__global__ void k_tr(const float* __restrict__ in, __bf16* __restrict__ oh,
                     __bf16* __restrict__ ol, int R, int C) {
  __shared__ float t[32][33];
  const float* im = in + (size_t)blockIdx.z * R * C;
  __bf16* ohm = oh + (size_t)blockIdx.z * R * C;
  __bf16* olm = LO ? (ol + (size_t)blockIdx.z * R * C) : nullptr;
  int c0 = blockIdx.x * 32, r0 = blockIdx.y * 32;
  int tx = threadIdx.x & 31, ty = threadIdx.x >> 5;
  #pragma unroll
  for (int k = 0; k < 32; k += 8)
    t[ty + k][tx] = im[(size_t)(r0 + ty + k) * C + c0 + tx];
  __syncthreads();
  #pragma unroll
  for (int k = 0; k < 32; k += 8) {
    float v = t[tx][ty + k];                       // = in[r0+tx][c0+ty+k]
    size_t o = (size_t)(c0 + ty + k) * R + r0 + tx;
    __bf16 h = (__bf16)v;
    ohm[o] = h;
    if (LO) olm[o] = (__bf16)(v - (float)h);
  }
}

// ---------- QKV projection: xb[4096,256] x Wt[which][h][e][d] -> Q,K (scaled Q), Vt ----------
__global__ __launch_bounds__(256) void k_qkv(
    const __bf16* __restrict__ xb, const __bf16* __restrict__ Wt,
    const float* __restrict__ bq, const float* __restrict__ bk, const float* __restrict__ bv,
    __bf16* __restrict__ Qb, __bf16* __restrict__ Kb, __bf16* __restrict__ Vtb) {
  const int w = threadIdx.x >> 6, lane = threadIdx.x & 63;
  const int g = lane >> 4, qc = lane & 15;
  const int which = blockIdx.z >> 3, h = blockIdx.z & 7;
  const int m0 = blockIdx.x * 64 + w * 16;
  const int n0 = blockIdx.y * 64;
  const __bf16* Wm = Wt + ((size_t)blockIdx.z << 16);
  const float* bias = (which == 0 ? bq : which == 1 ? bk : bv) + h * 256;
  f32x4 acc[4] = {};
  const __bf16* ap = xb + (m0 + qc) * 256 + g * 8;
  #pragma unroll
  for (int kk = 0; kk < 8; kk++) {
    bf16x8 af = ld8(ap + kk * 32);
    #pragma unroll
    for (int nt = 0; nt < 4; nt++) {
      bf16x8 bf = ld8(Wm + (n0 + nt * 16 + qc) * 256 + kk * 32 + g * 8);
      acc[nt] = mfma16(af, bf, acc[nt]);
    }
  }
  const int b = m0 >> 11, s0 = (m0 & 2047);
  const int bh = b * 8 + h;
  #pragma unroll
  for (int nt = 0; nt < 4; nt++) {
    const int e = n0 + nt * 16 + qc;
    const float be = bias[e];
    if (which == 2) {                // V: write transposed Vt[bh][e][s]
      bf16x4 pk;
      #pragma unroll
      for (int r = 0; r < 4; r++) pk[r] = (__bf16)(acc[nt][r] + be);
      *reinterpret_cast<bf16x4*>(Vtb + ((bh * 256 + e) * 2048 + s0 + g * 4)) = pk;
    } else {
      const float sc = (which == 0) ? 0.0625f : 1.0f;   // fold 1/sqrt(D) into Q
      __bf16* Out = (which == 0) ? Qb : Kb;
      #pragma unroll
      for (int r = 0; r < 4; r++)
        Out[(bh * 2048 + s0 + g * 4 + r) * 256 + e] = (__bf16)((acc[nt][r] + be) * sc);
    }
  }
}

// ---------- flash attention v2: 4 waves x 32 q-rows (32x32 MFMA), LDS-staged K/V ----------
// grid: (bh=16, qtile=16); block 256. LDS: K[64][256] + Vt[256][64] double-buffered,
// XOR-swizzled (off ^= (row&7)<<4) with pre-swizzled global_load_lds sources.
__global__ __launch_bounds__(256, 1) void k_attn(
    const __bf16* __restrict__ Qb, const __bf16* __restrict__ Kb,
    const __bf16* __restrict__ Vtb, __bf16* __restrict__ Oh, __bf16* __restrict__ Ol) {
  __shared__ __align__(16) unsigned char kbuf[2][32768];   // [64 kv][256 d] bf16, swz
  __shared__ __align__(16) unsigned char vbuf[2][32768];   // [256 d][64 kv] bf16, swz
  __shared__ __align__(16) unsigned char pbuf[4][4096];    // per-wave P[32 q][64 kv], swz
  const int tid = threadIdx.x;
  const int w = tid >> 6, lane = tid & 63;
  const int hi = lane >> 5, q = lane & 31;
  const int bh = blockIdx.x, qt = blockIdx.y;
  const int q0w = qt * 128 + w * 32;
  const char* Kg = (const char*)Kb + ((size_t)bh * 2048) * 512;   // K row = 512B
  const char* Vg = (const char*)Vtb + ((size_t)bh * 256) * 4096;  // Vt row = 4096B
  const __bf16* Qp = Qb + ((size_t)(bh * 2048 + q0w + q)) * 256;

  // Q B-frags (col=q, k-chunk kk): 8 bf16 at d = kk*16 + hi*8
  bf16x8 qf[16];
  #pragma unroll
  for (int kk = 0; kk < 16; kk++) qf[kk] = ld8(Qp + kk * 16 + hi * 8);

  f32x16 acc[8];
  #pragma unroll
  for (int i = 0; i < 8; i++)
    #pragma unroll
    for (int e = 0; e < 16; e++) acc[i][e] = 0.f;

  // cooperative staging: wave w stages K rows [16w,16w+16) and Vt rows [64w,64w+64)
  auto stage = [&](int nb, int t) {
    #pragma unroll
    for (int j = 0; j < 8; j++) {
      const int O = w * 8192 + j * 1024 + lane * 16;
      const int row = O >> 9;
      const int sc = ((O >> 4) & 31) ^ (row & 7);
      gl_lds16(Kg + (size_t)t * 32768 + (size_t)row * 512 + sc * 16,
               &kbuf[nb][w * 8192 + j * 1024]);
    }
    #pragma unroll
    for (int j = 0; j < 8; j++) {
      const int O = w * 8192 + j * 1024 + lane * 16;
      const int d = O >> 7;
      const int sv = ((O >> 4) & 7) ^ (d & 7);
      gl_lds16(Vg + (size_t)t * 128 + (size_t)d * 4096 + sv * 16,
               &vbuf[nb][w * 8192 + j * 1024]);
    }
  };

  float m_run = -3.0e38f, l_run = 0.f;
  stage(0, 0);
  __syncthreads();

  for (int t = 0; t < 32; t++) {
    const int cur = t & 1;
    if (t < 31) stage(cur ^ 1, t + 1);          // prefetch next tile (drained at barrier)

    // ---- QK^T (swapped): st[s] = S^T[kv=32s..][q], col=q=lane&31 ----
    f32x16 st[2];
    #pragma unroll
    for (int s = 0; s < 2; s++) {
      #pragma unroll
      for (int e = 0; e < 16; e++) st[s][e] = 0.f;
      const int kvr = s * 32 + q;
      const int swz = (kvr & 7) << 4;
      #pragma unroll
      for (int kk = 0; kk < 16; kk++) {
        const int off = (kvr * 512 + kk * 32 + hi * 16) ^ swz;
        bf16x8 kf = *reinterpret_cast<const bf16x8*>(&kbuf[cur][off]);
        st[s] = mfma32(kf, qf[kk], st[s]);
      }
    }

    // ---- online softmax (state per q = lane&31, dup across halves) ----
    float rmax = st[0][0];
    #pragma unroll
    for (int s = 0; s < 2; s++)
      #pragma unroll
      for (int r = 0; r < 16; r++) rmax = fmaxf(rmax, st[s][r]);
    rmax = fmaxf(rmax, __shfl_xor(rmax, 32));
    const bool nm = rmax > m_run;
    const float m_new = nm ? rmax : m_run;
    float p[2][16];
    float rs = 0.f;
    #pragma unroll
    for (int s = 0; s < 2; s++)
      #pragma unroll
      for (int r = 0; r < 16; r++) { p[s][r] = __expf(st[s][r] - m_new); rs += p[s][r]; }
    rs += __shfl_xor(rs, 32);
    if (__any(nm)) {
      const float alpha = __expf(m_run - m_new);
      l_run = l_run * alpha + rs;
      m_run = m_new;
      float ar[16];
      #pragma unroll
      for (int r = 0; r < 16; r++)
        ar[r] = __shfl(alpha, (r & 3) + 8 * (r >> 2) + 4 * hi);  // alpha of acc row q
      #pragma unroll
      for (int dt = 0; dt < 8; dt++)
        #pragma unroll
        for (int r = 0; r < 16; r++) acc[dt][r] *= ar[r];
    } else {
      l_run += rs;
    }

    // ---- P -> LDS (per-wave, swizzled), reload as A-frags ----
    #pragma unroll
    for (int s = 0; s < 2; s++)
      #pragma unroll
      for (int rq = 0; rq < 4; rq++) {
        bf16x4 pk;
        #pragma unroll
        for (int i = 0; i < 4; i++) pk[i] = (__bf16)p[s][rq * 4 + i];
        const int kv = s * 32 + rq * 8 + hi * 4;
        const int off = (q * 128 + kv * 2) ^ ((q & 7) << 4);
        *reinterpret_cast<bf16x4*>(&pbuf[w][off]) = pk;
      }
    bf16x8 pa[4];
    #pragma unroll
    for (int c = 0; c < 4; c++) {
      const int off = (q * 128 + c * 32 + hi * 16) ^ ((q & 7) << 4);
      pa[c] = *reinterpret_cast<const bf16x8*>(&pbuf[w][off]);
    }

    // ---- PV: O[q][d] += P[q][kv] * Vt[d][kv] ----
    #pragma unroll
    for (int dt = 0; dt < 8; dt++) {
      const int d = dt * 32 + q;
      const int swz = (d & 7) << 4;
      #pragma unroll
      for (int c = 0; c < 4; c++) {
        const int off = (d * 128 + c * 32 + hi * 16) ^ swz;
        bf16x8 vf = *reinterpret_cast<const bf16x8*>(&vbuf[cur][off]);
        acc[dt] = mfma32(pa[c], vf, acc[dt]);
      }
    }
    __syncthreads();   // drains staging vmcnt; all waves advance tiles together
  }

  // ---- epilogue: divide by l, split hi/lo bf16 ----
  float linv[16];
  #pragma unroll
  for (int r = 0; r < 16; r++)
    linv[r] = 1.f / __shfl(l_run, (r & 3) + 8 * (r >> 2) + 4 * hi);
  const int b = bh >> 3, h = bh & 7;
  #pragma unroll
  for (int dt = 0; dt < 8; dt++) {
    const int d = h * 256 + dt * 32 + q;
    #pragma unroll
    for (int r = 0; r < 16; r++) {
      const int qrow = (r & 3) + 8 * (r >> 2) + 4 * hi;
      const float v = acc[dt][r] * linv[r];
      const size_t off = (size_t)b * (2048 * 2048) + (size_t)(q0w + qrow) * 2048 + d;
      const __bf16 hv = (__bf16)v;
      Oh[off] = hv;
      Ol[off] = (__bf16)(v - (float)hv);
    }
  }
}

// ---------- output projection: concat[4096,2048] x Wo[2048,256], split-bf16 (3 terms) ----------
__global__ __launch_bounds__(256) void k_out(
    const __bf16* __restrict__ Oh, const __bf16* __restrict__ Ol,
    const __bf16* __restrict__ Wh, const __bf16* __restrict__ Wl,
    const float* __restrict__ bo, float* __restrict__ out) {
  const int w = threadIdx.x >> 6, lane = threadIdx.x & 63;
  const int g = lane >> 4, qc = lane & 15;
  const int m0 = blockIdx.x * 64 + w * 16, n0 = blockIdx.y * 64;
  f32x4 acc[4] = {};
  const __bf16* ah_p = Oh + (m0 + qc) * 2048 + g * 8;
  const __bf16* al_p = Ol + (m0 + qc) * 2048 + g * 8;
  for (int kk = 0; kk < 64; kk++) {
    bf16x8 ah = ld8(ah_p + kk * 32);
    bf16x8 al = ld8(al_p + kk * 32);
    #pragma unroll
    for (int nt = 0; nt < 4; nt++) {
      const int nrow = (n0 + nt * 16 + qc) * 2048 + kk * 32 + g * 8;
      bf16x8 bh = ld8(Wh + nrow);
      bf16x8 bl = ld8(Wl + nrow);
      acc[nt] = mfma16(ah, bh, acc[nt]);
      acc[nt] = mfma16(al, bh, acc[nt]);
      acc[nt] = mfma16(ah, bl, acc[nt]);
    }
  }
  #pragma unroll
  for (int nt = 0; nt < 4; nt++) {
    const int n = n0 + nt * 16 + qc;
    const float bb = bo[n];
    #pragma unroll
    for (int r = 0; r < 4; r++)
      out[(m0 + g * 4 + r) * 256 + n] = acc[nt][r] + bb;
  }
}

extern "C" void kernel_launch(void* const* d_in, const int* in_sizes, int n_in,
                              void* d_out, int out_size, void* d_ws, size_t ws_size,
                              hipStream_t stream) {
  const float* x  = (const float*)d_in[0];
  const float* Wq = (const float*)d_in[1];
  const float* bq = (const float*)d_in[2];
  const float* Wk = (const float*)d_in[3];
  const float* bk = (const float*)d_in[4];
  const float* Wv = (const float*)d_in[5];
  const float* bv = (const float*)d_in[6];
  const float* Wo = (const float*)d_in[7];
  const float* bo = (const float*)d_in[8];
  char* p = (char*)d_ws;
  __bf16* xb  = (__bf16*)(p);                          // 2 MB  [4096][256]
  __bf16* Wt  = (__bf16*)(p + (2ull  << 20));          // 3 MB  [3][8][256 e][256 d]
  __bf16* Woh = (__bf16*)(p + (5ull  << 20));          // 1 MB  [256 n][2048 k]
  __bf16* Wol = (__bf16*)(p + (6ull  << 20));          // 1 MB
  __bf16* Qb  = (__bf16*)(p + (7ull  << 20));          // 16 MB [bh][s][d]  (pre-scaled)
  __bf16* Kb  = (__bf16*)(p + (23ull << 20));          // 16 MB [bh][s][d]
  __bf16* Vtb = (__bf16*)(p + (39ull << 20));          // 16 MB [bh][d][s]
  __bf16* Ohb = (__bf16*)(p + (55ull << 20));          // 16 MB [bs][h*d] hi
  __bf16* Olb = (__bf16*)(p + (71ull << 20));          // 16 MB [bs][h*d] lo

  k_cvt<<<dim3(1024), dim3(256), 0, stream>>>(x, xb, 262144);
  k_tr<false><<<dim3(8, 8, 8),  dim3(256), 0, stream>>>(Wq, Wt + 0 * 524288, nullptr, 256, 256);
  k_tr<false><<<dim3(8, 8, 8),  dim3(256), 0, stream>>>(Wk, Wt + 1 * 524288, nullptr, 256, 256);
  k_tr<false><<<dim3(8, 8, 8),  dim3(256), 0, stream>>>(Wv, Wt + 2 * 524288, nullptr, 256, 256);
  k_tr<true ><<<dim3(8, 64, 1), dim3(256), 0, stream>>>(Wo, Woh, Wol, 2048, 256);
  k_qkv<<<dim3(64, 4, 24), dim3(256), 0, stream>>>(xb, Wt, bq, bk, bv, Qb, Kb, Vtb);
  k_attn<<<dim3(16, 16), dim3(256), 0, stream>>>(Qb, Kb, Vtb, Ohb, Olb);
  k_out<<<dim3(64, 4), dim3(256), 0, stream>>>(Ohb, Olb, Woh, Wol, bo, (float*)d_out);
}